// Round 7
// baseline (83.558 us; speedup 1.0000x reference)
//
#include <hip/hip_runtime.h>

#define B 16384
#define C 4
#define M 512
#define D 512
#define NCH 16
#define NSEG 64   // B/256 candidate segments

// ---------------- K1: stats + segmented candidate build (no atomics) -------
__global__ __launch_bounds__(256) void k1_stats(
    const float* __restrict__ logits,
    const float* __restrict__ ent_memo,
    float* __restrict__ out,
    int* __restrict__ blockCnt,
    uint2* __restrict__ candList,
    int* __restrict__ rnkB,
    int* __restrict__ rnkM)
{
    __shared__ int wscan[4];
    const int tid = threadIdx.x, blk = blockIdx.x;
    const int gid = blk * 256 + tid;

    float4 l = *reinterpret_cast<const float4*>(logits + (size_t)gid * 4);
    float m = l.x; int idx = 0;
    if (l.y > m) { m = l.y; idx = 1; }
    if (l.z > m) { m = l.z; idx = 2; }
    if (l.w > m) { m = l.w; idx = 3; }
    float e0 = expf(l.x - m), e1 = expf(l.y - m), e2 = expf(l.z - m), e3 = expf(l.w - m);
    float s = e0 + e1 + e2 + e3;
    float inv = 1.0f / s;
    float p0 = e0 * inv, p1 = e1 * inv, p2 = e2 * inv, p3 = e3 * inv;
    float lse = logf(s);
    float ent = -(p0 * (l.x - m - lse) + p1 * (l.y - m - lse)
                + p2 * (l.z - m - lse) + p3 * (l.w - m - lse));
    float4 pr = { p0, p1, p2, p3 };
    *reinterpret_cast<float4*>(out + (size_t)B * 4 + (size_t)gid * 4) = pr;
    out[(size_t)B * 8 + gid] = ent;

    rnkB[gid] = 0;
    if (gid < C * M) rnkM[gid] = 0;

    const float* Ac = ent_memo + (idx << 9);
    bool flag = ent < Ac[M - 1];
    unsigned lo = 0;
    if (flag) {
        int l0 = 0, hi = M;                  // upper_bound -> #{A <= ent}
        while (l0 < hi) { int mid = (l0 + hi) >> 1; if (Ac[mid] <= ent) l0 = mid + 1; else hi = mid; }
        lo = (unsigned)l0;
    }
    // block-level compaction (order = b ascending within segment)
    unsigned long long mask = __ballot(flag);
    int lane = tid & 63, wv = tid >> 6;
    int prefix = __popcll(mask & ((1ull << lane) - 1ull));
    if (lane == 0) wscan[wv] = __popcll(mask);
    __syncthreads();
    int base = 0;
    for (int w = 0; w < wv; w++) base += wscan[w];
    if (flag)
        candList[blk * 256 + base + prefix] =
            make_uint2(__float_as_uint(ent),
                       (lo << 16) | ((unsigned)idx << 14) | (unsigned)gid);
    if (tid == 0)
        blockCnt[blk] = wscan[0] + wscan[1] + wscan[2] + wscan[3];
}

// ---------------- K2a: pairwise stable-rank partial counts -----------------
// grid (NSEG+8, NCH): x<NSEG -> candidate-role block x; x>=NSEG -> memo rows.
__global__ __launch_bounds__(256) void k2a_count(
    const float* __restrict__ ent_memo,
    const int* __restrict__ blockCnt,
    const uint2* __restrict__ candList,
    int* __restrict__ rnkB,
    int* __restrict__ rnkM)
{
    __shared__ uint2 ch[1024];      // 4 candidate segments of this y-chunk
    const int x = blockIdx.x, y = blockIdx.y, tid = threadIdx.x;

    int s0 = blockCnt[4 * y + 0];
    int s1 = blockCnt[4 * y + 1];
    int s2 = blockCnt[4 * y + 2];
    int s3 = blockCnt[4 * y + 3];
    int o1 = s0, o2 = s0 + s1, o3 = o2 + s2, total = o3 + s3;
    for (int j = tid; j < s0; j += 256) ch[j]      = candList[(4 * y + 0) * 256 + j];
    for (int j = tid; j < s1; j += 256) ch[o1 + j] = candList[(4 * y + 1) * 256 + j];
    for (int j = tid; j < s2; j += 256) ch[o2 + j] = candList[(4 * y + 2) * 256 + j];
    for (int j = tid; j < s3; j += 256) ch[o3 + j] = candList[(4 * y + 3) * 256 + j];
    __syncthreads();

    if (x < NSEG) {
        if (tid < blockCnt[x]) {
            uint2 v = candList[x * 256 + tid];
            float e = __uint_as_float(v.x);
            int lab = (int)((v.y >> 14) & 3);
            int bidx = (int)(v.y & 0x3FFF);
            int r = 0;
            for (int i = 0; i < total; i++) {
                uint2 w = ch[i];
                float e2 = __uint_as_float(w.x);
                if ((int)((w.y >> 14) & 3) == lab &&
                    (e2 < e || (e2 == e && (int)(w.y & 0x3FFF) < bidx))) r++;
            }
            if (r) atomicAdd(&rnkB[x * 256 + tid], r);
        }
    } else {
        int t = (x - NSEG) * 256 + tid;       // [0, C*M)
        float Am = ent_memo[t];
        int mc = t >> 9;
        int rm = 0;
        for (int i = 0; i < total; i++) {
            uint2 w = ch[i];
            if ((int)((w.y >> 14) & 3) == mc && __uint_as_float(w.x) < Am) rm++;
        }
        if (rm) atomicAdd(&rnkM[t], rm);
    }
}

// ---------------- K4: rebuild 16-row window + partial row-sums -------------
// 128 blocks: c = blk>>5, seg = blk&31 (rows seg*16..seg*16+15 of kept list).
__global__ __launch_bounds__(256) void k4_partial(
    const int* __restrict__ blockCnt,
    const uint2* __restrict__ candList,
    const int* __restrict__ rnkB,
    const int* __restrict__ rnkM,
    const float* __restrict__ text_memo,
    const float* __restrict__ text_embeds,
    float* __restrict__ part)
{
    __shared__ int le[16];
    __shared__ int cnts[NSEG];
    const int blk = blockIdx.x;
    const int c = blk >> 5, seg = blk & 31;
    const int tid = threadIdx.x;
    const int wlo = seg * 16, whi = wlo + 16;

    if (tid < NSEG) cnts[tid] = blockCnt[tid];
    __syncthreads();

    // memo rows of label c: rank = i + rnkM
    for (int i = tid; i < M; i += 256) {
        int r = i + rnkM[(c << 9) + i];
        if (r >= wlo && r < whi) le[r - wlo] = i;
    }
    // batch candidates: rank = lo + rnkB
    for (int slot = tid; slot < B; slot += 256) {
        int sg = slot >> 8, j = slot & 255;
        if (j < cnts[sg]) {
            uint2 v = candList[slot];
            if ((int)((v.y >> 14) & 3) == c) {
                int r = (int)(v.y >> 16) + rnkB[slot];
                if (r >= wlo && r < whi) le[r - wlo] = 0x10000 | (int)(v.y & 0x3FFF);
            }
        }
    }
    __syncthreads();

    float a0 = 0.0f, a1 = 0.0f;
    for (int j = 0; j < 16; j++) {
        int e = le[j];
        const float* row = (e & 0x10000)
            ? (text_embeds + (size_t)(e & 0x3FFF) * D)
            : (text_memo + (size_t)((c << 9) | (e & (M - 1))) * D);
        a0 += row[tid];
        a1 += row[tid + 256];
    }
    part[(size_t)blk * D + tid] = a0;
    part[(size_t)blk * D + tid + 256] = a1;
}

// ---------------- K5: part->S reduce (per block) + GEMV + softmaxes --------
// 256 blocks x 256 thr; each block reduces part into LDS Sl then does 64 rows.
__global__ __launch_bounds__(256) void k5_cosin(
    const float* __restrict__ part,
    const float* __restrict__ text_embeds,
    float* __restrict__ out)
{
    __shared__ float Sl[C * D];      // 8 KB
    const int tid = threadIdx.x;

    // cooperative reduce: thread handles entries tid + k*256 (k=0..7)
    #pragma unroll
    for (int k = 0; k < 8; k++) {
        int e = tid + k * 256;       // (c,d): c = e>>9, d = e&511
        int c = e >> 9, d = e & (D - 1);
        float s = 0.0f;
        for (int sg = 0; sg < 32; sg++)
            s += part[(size_t)((c << 5) + sg) * D + d];
        Sl[e] = s;
    }
    __syncthreads();

    const int wave = tid >> 6, lane = tid & 63;
    for (int r4 = 0; r4 < 16; r4++) {
        int b = blockIdx.x * 64 + wave * 16 + r4;
        const float4* te4 = reinterpret_cast<const float4*>(text_embeds + (size_t)b * D);
        float4 t0 = te4[lane * 2], t1 = te4[lane * 2 + 1];
        const float4* S4 = reinterpret_cast<const float4*>(Sl);
        float c0, c1, c2, c3;
        {
            float4 a0 = S4[0 * 128 + lane * 2], a1 = S4[0 * 128 + lane * 2 + 1];
            c0 = t0.x*a0.x + t0.y*a0.y + t0.z*a0.z + t0.w*a0.w
               + t1.x*a1.x + t1.y*a1.y + t1.z*a1.z + t1.w*a1.w;
        }
        {
            float4 a0 = S4[1 * 128 + lane * 2], a1 = S4[1 * 128 + lane * 2 + 1];
            c1 = t0.x*a0.x + t0.y*a0.y + t0.z*a0.z + t0.w*a0.w
               + t1.x*a1.x + t1.y*a1.y + t1.z*a1.z + t1.w*a1.w;
        }
        {
            float4 a0 = S4[2 * 128 + lane * 2], a1 = S4[2 * 128 + lane * 2 + 1];
            c2 = t0.x*a0.x + t0.y*a0.y + t0.z*a0.z + t0.w*a0.w
               + t1.x*a1.x + t1.y*a1.y + t1.z*a1.z + t1.w*a1.w;
        }
        {
            float4 a0 = S4[3 * 128 + lane * 2], a1 = S4[3 * 128 + lane * 2 + 1];
            c3 = t0.x*a0.x + t0.y*a0.y + t0.z*a0.z + t0.w*a0.w
               + t1.x*a1.x + t1.y*a1.y + t1.z*a1.z + t1.w*a1.w;
        }
        for (int off = 32; off; off >>= 1) {
            c0 += __shfl_down(c0, off, 64);
            c1 += __shfl_down(c1, off, 64);
            c2 += __shfl_down(c2, off, 64);
            c3 += __shfl_down(c3, off, 64);
        }
        if (lane == 0) {
            float t0c = c0 + c2, t1c = c1 + c3;   // text_combine
            float v0c = c0 + c1, v1c = c2 + c3;   // vision_combine
            float tm = fmaxf(t0c, t1c);
            float te0 = expf(t0c - tm), te1 = expf(t1c - tm);
            float ts = te0 + te1;
            float mt0 = te0 / ts, mt1 = te1 / ts;
            float vm = fmaxf(v0c, v1c);
            float ve0 = expf(v0c - vm), ve1 = expf(v1c - vm);
            float vs = ve0 + ve1;
            float mv0 = ve0 / vs, mv1 = ve1 / vs;
            float4 o = { mt0 * mv0, mt1 * mv0, mt0 * mv1, mt1 * mv1 };
            *reinterpret_cast<float4*>(out + (size_t)b * 4) = o;
        }
    }
}

// ---------------------------------------------------------------------------
extern "C" void kernel_launch(void* const* d_in, const int* in_sizes, int n_in,
                              void* d_out, int out_size, void* d_ws, size_t ws_size,
                              hipStream_t stream)
{
    (void)in_sizes; (void)n_in; (void)out_size; (void)ws_size;
    const float* logits      = (const float*)d_in[0];
    const float* text_embeds = (const float*)d_in[1];
    const float* ent_memo    = (const float*)d_in[3];
    const float* text_memo   = (const float*)d_in[4];
    float* out = (float*)d_out;
    char* ws = (char*)d_ws;

    // workspace layout (bytes), 256-aligned
    int*   blockCnt = (int*)(ws + 0);          // 256 B
    uint2* candList = (uint2*)(ws + 256);      // 128 KB  -> 131328
    int*   rnkB     = (int*)(ws + 131328);     // 64 KB   -> 196864
    int*   rnkM     = (int*)(ws + 196864);     // 8 KB    -> 205056
    float* part     = (float*)(ws + 205056);   // 256 KB  -> 467200

    k1_stats<<<NSEG, 256, 0, stream>>>(logits, ent_memo, out, blockCnt,
                                       candList, rnkB, rnkM);
    k2a_count<<<dim3(NSEG + 8, NCH), 256, 0, stream>>>(ent_memo, blockCnt,
                                                       candList, rnkB, rnkM);
    k4_partial<<<128, 256, 0, stream>>>(blockCnt, candList, rnkB, rnkM,
                                        text_memo, text_embeds, part);
    k5_cosin<<<B / 64, 256, 0, stream>>>(part, text_embeds, out);
}

// Round 8
// 76.826 us; speedup vs baseline: 1.0876x; 1.0876x over previous
//
#include <hip/hip_runtime.h>

#define B 16384
#define C 4
#define M 512
#define D 512
#define NCH 16
#define NSEG 64   // B/256 candidate segments

// ---------------- K1: stats + segmented candidate build (no atomics) -------
__global__ __launch_bounds__(256) void k1_stats(
    const float* __restrict__ logits,
    const float* __restrict__ ent_memo,
    float* __restrict__ out,
    int* __restrict__ blockCnt,
    uint2* __restrict__ candList,
    int* __restrict__ rnkB,
    int* __restrict__ rnkM)
{
    __shared__ int wscan[4];
    const int tid = threadIdx.x, blk = blockIdx.x;
    const int gid = blk * 256 + tid;

    float4 l = *reinterpret_cast<const float4*>(logits + (size_t)gid * 4);
    float m = l.x; int idx = 0;
    if (l.y > m) { m = l.y; idx = 1; }
    if (l.z > m) { m = l.z; idx = 2; }
    if (l.w > m) { m = l.w; idx = 3; }
    float e0 = expf(l.x - m), e1 = expf(l.y - m), e2 = expf(l.z - m), e3 = expf(l.w - m);
    float s = e0 + e1 + e2 + e3;
    float inv = 1.0f / s;
    float p0 = e0 * inv, p1 = e1 * inv, p2 = e2 * inv, p3 = e3 * inv;
    float lse = logf(s);
    float ent = -(p0 * (l.x - m - lse) + p1 * (l.y - m - lse)
                + p2 * (l.z - m - lse) + p3 * (l.w - m - lse));
    float4 pr = { p0, p1, p2, p3 };
    *reinterpret_cast<float4*>(out + (size_t)B * 4 + (size_t)gid * 4) = pr;
    out[(size_t)B * 8 + gid] = ent;

    rnkB[gid] = 0;
    if (gid < C * M) rnkM[gid] = 0;

    const float* Ac = ent_memo + (idx << 9);
    bool flag = ent < Ac[M - 1];
    unsigned lo = 0;
    if (flag) {
        int l0 = 0, hi = M;                  // upper_bound -> #{A <= ent}
        while (l0 < hi) { int mid = (l0 + hi) >> 1; if (Ac[mid] <= ent) l0 = mid + 1; else hi = mid; }
        lo = (unsigned)l0;
    }
    // block-level compaction (order = b ascending within segment)
    unsigned long long mask = __ballot(flag);
    int lane = tid & 63, wv = tid >> 6;
    int prefix = __popcll(mask & ((1ull << lane) - 1ull));
    if (lane == 0) wscan[wv] = __popcll(mask);
    __syncthreads();
    int base = 0;
    for (int w = 0; w < wv; w++) base += wscan[w];
    if (flag)
        candList[blk * 256 + base + prefix] =
            make_uint2(__float_as_uint(ent),
                       (lo << 16) | ((unsigned)idx << 14) | (unsigned)gid);
    if (tid == 0)
        blockCnt[blk] = wscan[0] + wscan[1] + wscan[2] + wscan[3];
}

// ---------------- K2a: pairwise stable-rank partial counts -----------------
// grid (NSEG+8, NCH): x<NSEG -> candidate-role block x; x>=NSEG -> memo rows.
__global__ __launch_bounds__(256) void k2a_count(
    const float* __restrict__ ent_memo,
    const int* __restrict__ blockCnt,
    const uint2* __restrict__ candList,
    int* __restrict__ rnkB,
    int* __restrict__ rnkM)
{
    __shared__ uint2 ch[1024];      // 4 candidate segments of this y-chunk
    const int x = blockIdx.x, y = blockIdx.y, tid = threadIdx.x;

    int s0 = blockCnt[4 * y + 0];
    int s1 = blockCnt[4 * y + 1];
    int s2 = blockCnt[4 * y + 2];
    int s3 = blockCnt[4 * y + 3];
    int o1 = s0, o2 = s0 + s1, o3 = o2 + s2, total = o3 + s3;
    for (int j = tid; j < s0; j += 256) ch[j]      = candList[(4 * y + 0) * 256 + j];
    for (int j = tid; j < s1; j += 256) ch[o1 + j] = candList[(4 * y + 1) * 256 + j];
    for (int j = tid; j < s2; j += 256) ch[o2 + j] = candList[(4 * y + 2) * 256 + j];
    for (int j = tid; j < s3; j += 256) ch[o3 + j] = candList[(4 * y + 3) * 256 + j];
    __syncthreads();

    if (x < NSEG) {
        if (tid < blockCnt[x]) {
            uint2 v = candList[x * 256 + tid];
            float e = __uint_as_float(v.x);
            int lab = (int)((v.y >> 14) & 3);
            int bidx = (int)(v.y & 0x3FFF);
            int r = 0;
            for (int i = 0; i < total; i++) {
                uint2 w = ch[i];
                float e2 = __uint_as_float(w.x);
                if ((int)((w.y >> 14) & 3) == lab &&
                    (e2 < e || (e2 == e && (int)(w.y & 0x3FFF) < bidx))) r++;
            }
            if (r) atomicAdd(&rnkB[x * 256 + tid], r);
        }
    } else {
        int t = (x - NSEG) * 256 + tid;       // [0, C*M)
        float Am = ent_memo[t];
        int mc = t >> 9;
        int rm = 0;
        for (int i = 0; i < total; i++) {
            uint2 w = ch[i];
            if ((int)((w.y >> 14) & 3) == mc && __uint_as_float(w.x) < Am) rm++;
        }
        if (rm) atomicAdd(&rnkM[t], rm);
    }
}

// ---------------- K4: rebuild 32-row window + partial row-sums -------------
// 64 blocks: c = blk>>4, seg = blk&15 (ranks seg*32..seg*32+31 of kept list).
__global__ __launch_bounds__(256) void k4_partial(
    const int* __restrict__ blockCnt,
    const uint2* __restrict__ candList,
    const int* __restrict__ rnkB,
    const int* __restrict__ rnkM,
    const float* __restrict__ text_memo,
    const float* __restrict__ text_embeds,
    float* __restrict__ part)
{
    __shared__ int le[32];
    __shared__ int cnts[NSEG];
    const int blk = blockIdx.x;
    const int c = blk >> 4, seg = blk & 15;
    const int tid = threadIdx.x;
    const int wlo = seg * 32, whi = wlo + 32;

    if (tid < NSEG) cnts[tid] = blockCnt[tid];
    __syncthreads();

    // memo rows of label c: rank = i + rnkM  (2 coalesced iterations)
    for (int i = tid; i < M; i += 256) {
        int r = i + rnkM[(c << 9) + i];
        if (r >= wlo && r < whi) le[r - wlo] = i;
    }
    // batch candidates: rank = lo + rnkB — branch-free loads, predicated write
    #pragma unroll 8
    for (int slot = tid; slot < B; slot += 256) {
        uint2 v = candList[slot];          // unconditional (allocated; garbage ok)
        int rb = rnkB[slot];               // unconditional (zero-init'd)
        int sg = slot >> 8, j = slot & 255;
        if (j < cnts[sg] && (int)((v.y >> 14) & 3) == c) {
            int r = (int)(v.y >> 16) + rb;
            if (r >= wlo && r < whi) le[r - wlo] = 0x10000 | (int)(v.y & 0x3FFF);
        }
    }
    __syncthreads();

    float a0 = 0.0f, a1 = 0.0f;
    #pragma unroll 4
    for (int j = 0; j < 32; j++) {
        int e = le[j];
        const float* row = (e & 0x10000)
            ? (text_embeds + (size_t)(e & 0x3FFF) * D)
            : (text_memo + (size_t)((c << 9) | (e & (M - 1))) * D);
        a0 += row[tid];
        a1 += row[tid + 256];
    }
    part[(size_t)blk * D + tid] = a0;
    part[(size_t)blk * D + tid + 256] = a1;
}

// ---------------- K5: part->S reduce (per block) + GEMV + softmaxes --------
// 256 blocks x 256 thr; each block reduces part into LDS Sl then does 64 rows.
__global__ __launch_bounds__(256) void k5_cosin(
    const float* __restrict__ part,
    const float* __restrict__ text_embeds,
    float* __restrict__ out)
{
    __shared__ float Sl[C * D];      // 8 KB
    const int tid = threadIdx.x;

    #pragma unroll
    for (int k = 0; k < 8; k++) {
        int e = tid + k * 256;       // (c,d): c = e>>9, d = e&511
        int c = e >> 9, d = e & (D - 1);
        float s = 0.0f;
        #pragma unroll 4
        for (int sg = 0; sg < 16; sg++)
            s += part[(size_t)((c << 4) + sg) * D + d];
        Sl[e] = s;
    }
    __syncthreads();

    const int wave = tid >> 6, lane = tid & 63;
    for (int r4 = 0; r4 < 16; r4++) {
        int b = blockIdx.x * 64 + wave * 16 + r4;
        const float4* te4 = reinterpret_cast<const float4*>(text_embeds + (size_t)b * D);
        float4 t0 = te4[lane * 2], t1 = te4[lane * 2 + 1];
        const float4* S4 = reinterpret_cast<const float4*>(Sl);
        float c0, c1, c2, c3;
        {
            float4 a0 = S4[0 * 128 + lane * 2], a1 = S4[0 * 128 + lane * 2 + 1];
            c0 = t0.x*a0.x + t0.y*a0.y + t0.z*a0.z + t0.w*a0.w
               + t1.x*a1.x + t1.y*a1.y + t1.z*a1.z + t1.w*a1.w;
        }
        {
            float4 a0 = S4[1 * 128 + lane * 2], a1 = S4[1 * 128 + lane * 2 + 1];
            c1 = t0.x*a0.x + t0.y*a0.y + t0.z*a0.z + t0.w*a0.w
               + t1.x*a1.x + t1.y*a1.y + t1.z*a1.z + t1.w*a1.w;
        }
        {
            float4 a0 = S4[2 * 128 + lane * 2], a1 = S4[2 * 128 + lane * 2 + 1];
            c2 = t0.x*a0.x + t0.y*a0.y + t0.z*a0.z + t0.w*a0.w
               + t1.x*a1.x + t1.y*a1.y + t1.z*a1.z + t1.w*a1.w;
        }
        {
            float4 a0 = S4[3 * 128 + lane * 2], a1 = S4[3 * 128 + lane * 2 + 1];
            c3 = t0.x*a0.x + t0.y*a0.y + t0.z*a0.z + t0.w*a0.w
               + t1.x*a1.x + t1.y*a1.y + t1.z*a1.z + t1.w*a1.w;
        }
        for (int off = 32; off; off >>= 1) {
            c0 += __shfl_down(c0, off, 64);
            c1 += __shfl_down(c1, off, 64);
            c2 += __shfl_down(c2, off, 64);
            c3 += __shfl_down(c3, off, 64);
        }
        if (lane == 0) {
            float t0c = c0 + c2, t1c = c1 + c3;   // text_combine
            float v0c = c0 + c1, v1c = c2 + c3;   // vision_combine
            float tm = fmaxf(t0c, t1c);
            float te0 = expf(t0c - tm), te1 = expf(t1c - tm);
            float ts = te0 + te1;
            float mt0 = te0 / ts, mt1 = te1 / ts;
            float vm = fmaxf(v0c, v1c);
            float ve0 = expf(v0c - vm), ve1 = expf(v1c - vm);
            float vs = ve0 + ve1;
            float mv0 = ve0 / vs, mv1 = ve1 / vs;
            float4 o = { mt0 * mv0, mt1 * mv0, mt0 * mv1, mt1 * mv1 };
            *reinterpret_cast<float4*>(out + (size_t)b * 4) = o;
        }
    }
}

// ---------------------------------------------------------------------------
extern "C" void kernel_launch(void* const* d_in, const int* in_sizes, int n_in,
                              void* d_out, int out_size, void* d_ws, size_t ws_size,
                              hipStream_t stream)
{
    (void)in_sizes; (void)n_in; (void)out_size; (void)ws_size;
    const float* logits      = (const float*)d_in[0];
    const float* text_embeds = (const float*)d_in[1];
    const float* ent_memo    = (const float*)d_in[3];
    const float* text_memo   = (const float*)d_in[4];
    float* out = (float*)d_out;
    char* ws = (char*)d_ws;

    // workspace layout (bytes), 256-aligned
    int*   blockCnt = (int*)(ws + 0);          // 256 B
    uint2* candList = (uint2*)(ws + 256);      // 128 KB  -> 131328
    int*   rnkB     = (int*)(ws + 131328);     // 64 KB   -> 196864
    int*   rnkM     = (int*)(ws + 196864);     // 8 KB    -> 205056
    float* part     = (float*)(ws + 205056);   // 128 KB  -> 336128

    k1_stats<<<NSEG, 256, 0, stream>>>(logits, ent_memo, out, blockCnt,
                                       candList, rnkB, rnkM);
    k2a_count<<<dim3(NSEG + 8, NCH), 256, 0, stream>>>(ent_memo, blockCnt,
                                                       candList, rnkB, rnkM);
    k4_partial<<<64, 256, 0, stream>>>(blockCnt, candList, rnkB, rnkM,
                                       text_memo, text_embeds, part);
    k5_cosin<<<B / 64, 256, 0, stream>>>(part, text_embeds, out);
}

// Round 9
// 65.693 us; speedup vs baseline: 1.2719x; 1.1695x over previous
//
#include <hip/hip_runtime.h>

#define B 16384
#define C 4
#define M 512
#define D 512
#define NCH 16
#define NSEG 64   // B/256 candidate segments

// ---------------- K1: stats + segmented candidate build (no atomics) -------
__global__ __launch_bounds__(256) void k1_stats(
    const float* __restrict__ logits,
    const float* __restrict__ ent_memo,
    float* __restrict__ out,
    int* __restrict__ blockCnt,
    uint2* __restrict__ candList,
    int* __restrict__ rnkB,
    int* __restrict__ rnkM)
{
    __shared__ int wscan[4];
    const int tid = threadIdx.x, blk = blockIdx.x;
    const int gid = blk * 256 + tid;

    float4 l = *reinterpret_cast<const float4*>(logits + (size_t)gid * 4);
    float m = l.x; int idx = 0;
    if (l.y > m) { m = l.y; idx = 1; }
    if (l.z > m) { m = l.z; idx = 2; }
    if (l.w > m) { m = l.w; idx = 3; }
    float e0 = expf(l.x - m), e1 = expf(l.y - m), e2 = expf(l.z - m), e3 = expf(l.w - m);
    float s = e0 + e1 + e2 + e3;
    float inv = 1.0f / s;
    float p0 = e0 * inv, p1 = e1 * inv, p2 = e2 * inv, p3 = e3 * inv;
    float lse = logf(s);
    float ent = -(p0 * (l.x - m - lse) + p1 * (l.y - m - lse)
                + p2 * (l.z - m - lse) + p3 * (l.w - m - lse));
    float4 pr = { p0, p1, p2, p3 };
    *reinterpret_cast<float4*>(out + (size_t)B * 4 + (size_t)gid * 4) = pr;
    out[(size_t)B * 8 + gid] = ent;

    rnkB[gid] = 0;
    if (gid < C * M) rnkM[gid] = 0;

    const float* Ac = ent_memo + (idx << 9);
    bool flag = ent < Ac[M - 1];
    unsigned lo = 0;
    if (flag) {
        int l0 = 0, hi = M;                  // upper_bound -> #{A <= ent}
        while (l0 < hi) { int mid = (l0 + hi) >> 1; if (Ac[mid] <= ent) l0 = mid + 1; else hi = mid; }
        lo = (unsigned)l0;
    }
    // block-level compaction (order = b ascending within segment)
    unsigned long long mask = __ballot(flag);
    int lane = tid & 63, wv = tid >> 6;
    int prefix = __popcll(mask & ((1ull << lane) - 1ull));
    if (lane == 0) wscan[wv] = __popcll(mask);
    __syncthreads();
    int base = 0;
    for (int w = 0; w < wv; w++) base += wscan[w];
    if (flag)
        candList[blk * 256 + base + prefix] =
            make_uint2(__float_as_uint(ent),
                       (lo << 16) | ((unsigned)idx << 14) | (unsigned)gid);
    if (tid == 0)
        blockCnt[blk] = wscan[0] + wscan[1] + wscan[2] + wscan[3];
}

// ---------------- K2a: pairwise stable-rank partial counts -----------------
// grid (NSEG+8, NCH): x<NSEG -> candidate-role block x; x>=NSEG -> memo rows.
__global__ __launch_bounds__(256) void k2a_count(
    const float* __restrict__ ent_memo,
    const int* __restrict__ blockCnt,
    const uint2* __restrict__ candList,
    int* __restrict__ rnkB,
    int* __restrict__ rnkM)
{
    __shared__ uint2 ch[1024];      // 4 candidate segments of this y-chunk
    const int x = blockIdx.x, y = blockIdx.y, tid = threadIdx.x;

    int s0 = blockCnt[4 * y + 0];
    int s1 = blockCnt[4 * y + 1];
    int s2 = blockCnt[4 * y + 2];
    int s3 = blockCnt[4 * y + 3];
    int o1 = s0, o2 = s0 + s1, o3 = o2 + s2, total = o3 + s3;
    for (int j = tid; j < s0; j += 256) ch[j]      = candList[(4 * y + 0) * 256 + j];
    for (int j = tid; j < s1; j += 256) ch[o1 + j] = candList[(4 * y + 1) * 256 + j];
    for (int j = tid; j < s2; j += 256) ch[o2 + j] = candList[(4 * y + 2) * 256 + j];
    for (int j = tid; j < s3; j += 256) ch[o3 + j] = candList[(4 * y + 3) * 256 + j];
    __syncthreads();

    if (x < NSEG) {
        if (tid < blockCnt[x]) {
            uint2 v = candList[x * 256 + tid];
            float e = __uint_as_float(v.x);
            int lab = (int)((v.y >> 14) & 3);
            int bidx = (int)(v.y & 0x3FFF);
            int r = 0;
            for (int i = 0; i < total; i++) {
                uint2 w = ch[i];
                float e2 = __uint_as_float(w.x);
                if ((int)((w.y >> 14) & 3) == lab &&
                    (e2 < e || (e2 == e && (int)(w.y & 0x3FFF) < bidx))) r++;
            }
            if (r) atomicAdd(&rnkB[x * 256 + tid], r);
        }
    } else {
        int t = (x - NSEG) * 256 + tid;       // [0, C*M)
        float Am = ent_memo[t];
        int mc = t >> 9;
        int rm = 0;
        for (int i = 0; i < total; i++) {
            uint2 w = ch[i];
            if ((int)((w.y >> 14) & 3) == mc && __uint_as_float(w.x) < Am) rm++;
        }
        if (rm) atomicAdd(&rnkM[t], rm);
    }
}

// ---------------- K2b: rank-bijection scatter (one coalesced pass) ---------
// 64 blocks; block == candidate segment. Blocks 0..7 also scatter memo rows.
__global__ __launch_bounds__(256) void k2b_scatter(
    const int* __restrict__ blockCnt,
    const uint2* __restrict__ candList,
    const int* __restrict__ rnkB,
    const int* __restrict__ rnkM,
    int* __restrict__ list)
{
    const int tid = threadIdx.x, blk = blockIdx.x;
    const int gid = blk * 256 + tid;
    // memo rows: rank = i + rnkM[i]
    if (gid < C * M) {
        int r = (gid & (M - 1)) + rnkM[gid];
        if (r < M) list[(gid & ~(M - 1)) + r] = gid & (M - 1);
    }
    // batch candidates of this segment: rank = lo + rnkB
    uint2 v = candList[gid];           // unconditional (allocated)
    int rb = rnkB[gid];                // unconditional (zero-init'd)
    if (tid < blockCnt[blk]) {
        int r = (int)(v.y >> 16) + rb;
        if (r < M) list[(((v.y >> 14) & 3) << 9) + r] = 0x10000 | (int)(v.y & 0x3FFF);
    }
}

// ---------------- K4: gather 32 kept rows per block -> part ---------------
// 64 blocks: c = blk>>4, window = (blk&15)*32 ranks.
__global__ __launch_bounds__(256) void k4_partial(
    const int* __restrict__ list,
    const float* __restrict__ text_memo,
    const float* __restrict__ text_embeds,
    float* __restrict__ part)
{
    __shared__ int le[32];
    const int blk = blockIdx.x;
    const int c = blk >> 4, wlo = (blk & 15) * 32;
    const int tid = threadIdx.x;

    if (tid < 32) le[tid] = list[(c << 9) + wlo + tid];
    __syncthreads();

    float a0 = 0.0f, a1 = 0.0f;
    #pragma unroll 8
    for (int j = 0; j < 32; j++) {
        int e = le[j];
        const float* row = (e & 0x10000)
            ? (text_embeds + (size_t)(e & 0x3FFF) * D)
            : (text_memo + (size_t)((c << 9) | (e & (M - 1))) * D);
        a0 += row[tid];
        a1 += row[tid + 256];
    }
    part[(size_t)blk * D + tid] = a0;
    part[(size_t)blk * D + tid + 256] = a1;
}

// ---------------- K5: part->S reduce (per block) + GEMV + softmaxes --------
// 256 blocks x 256 thr; each block reduces part into LDS Sl then does 64 rows.
__global__ __launch_bounds__(256) void k5_cosin(
    const float* __restrict__ part,
    const float* __restrict__ text_embeds,
    float* __restrict__ out)
{
    __shared__ float Sl[C * D];      // 8 KB
    const int tid = threadIdx.x;

    #pragma unroll
    for (int k = 0; k < 8; k++) {
        int e = tid + k * 256;       // (c,d): c = e>>9, d = e&511
        int c = e >> 9, d = e & (D - 1);
        float s = 0.0f;
        #pragma unroll 4
        for (int sg = 0; sg < 16; sg++)
            s += part[(size_t)((c << 4) + sg) * D + d];
        Sl[e] = s;
    }
    __syncthreads();

    const int wave = tid >> 6, lane = tid & 63;
    for (int r4 = 0; r4 < 16; r4++) {
        int b = blockIdx.x * 64 + wave * 16 + r4;
        const float4* te4 = reinterpret_cast<const float4*>(text_embeds + (size_t)b * D);
        float4 t0 = te4[lane * 2], t1 = te4[lane * 2 + 1];
        const float4* S4 = reinterpret_cast<const float4*>(Sl);
        float c0, c1, c2, c3;
        {
            float4 a0 = S4[0 * 128 + lane * 2], a1 = S4[0 * 128 + lane * 2 + 1];
            c0 = t0.x*a0.x + t0.y*a0.y + t0.z*a0.z + t0.w*a0.w
               + t1.x*a1.x + t1.y*a1.y + t1.z*a1.z + t1.w*a1.w;
        }
        {
            float4 a0 = S4[1 * 128 + lane * 2], a1 = S4[1 * 128 + lane * 2 + 1];
            c1 = t0.x*a0.x + t0.y*a0.y + t0.z*a0.z + t0.w*a0.w
               + t1.x*a1.x + t1.y*a1.y + t1.z*a1.z + t1.w*a1.w;
        }
        {
            float4 a0 = S4[2 * 128 + lane * 2], a1 = S4[2 * 128 + lane * 2 + 1];
            c2 = t0.x*a0.x + t0.y*a0.y + t0.z*a0.z + t0.w*a0.w
               + t1.x*a1.x + t1.y*a1.y + t1.z*a1.z + t1.w*a1.w;
        }
        {
            float4 a0 = S4[3 * 128 + lane * 2], a1 = S4[3 * 128 + lane * 2 + 1];
            c3 = t0.x*a0.x + t0.y*a0.y + t0.z*a0.z + t0.w*a0.w
               + t1.x*a1.x + t1.y*a1.y + t1.z*a1.z + t1.w*a1.w;
        }
        for (int off = 32; off; off >>= 1) {
            c0 += __shfl_down(c0, off, 64);
            c1 += __shfl_down(c1, off, 64);
            c2 += __shfl_down(c2, off, 64);
            c3 += __shfl_down(c3, off, 64);
        }
        if (lane == 0) {
            float t0c = c0 + c2, t1c = c1 + c3;   // text_combine
            float v0c = c0 + c1, v1c = c2 + c3;   // vision_combine
            float tm = fmaxf(t0c, t1c);
            float te0 = expf(t0c - tm), te1 = expf(t1c - tm);
            float ts = te0 + te1;
            float mt0 = te0 / ts, mt1 = te1 / ts;
            float vm = fmaxf(v0c, v1c);
            float ve0 = expf(v0c - vm), ve1 = expf(v1c - vm);
            float vs = ve0 + ve1;
            float mv0 = ve0 / vs, mv1 = ve1 / vs;
            float4 o = { mt0 * mv0, mt1 * mv0, mt0 * mv1, mt1 * mv1 };
            *reinterpret_cast<float4*>(out + (size_t)b * 4) = o;
        }
    }
}

// ---------------------------------------------------------------------------
extern "C" void kernel_launch(void* const* d_in, const int* in_sizes, int n_in,
                              void* d_out, int out_size, void* d_ws, size_t ws_size,
                              hipStream_t stream)
{
    (void)in_sizes; (void)n_in; (void)out_size; (void)ws_size;
    const float* logits      = (const float*)d_in[0];
    const float* text_embeds = (const float*)d_in[1];
    const float* ent_memo    = (const float*)d_in[3];
    const float* text_memo   = (const float*)d_in[4];
    float* out = (float*)d_out;
    char* ws = (char*)d_ws;

    // workspace layout (bytes), 256-aligned
    int*   blockCnt = (int*)(ws + 0);          // 256 B
    uint2* candList = (uint2*)(ws + 256);      // 128 KB  -> 131328
    int*   rnkB     = (int*)(ws + 131328);     // 64 KB   -> 196864
    int*   rnkM     = (int*)(ws + 196864);     // 8 KB    -> 205056
    int*   list     = (int*)(ws + 205056);     // 8 KB    -> 213248
    float* part     = (float*)(ws + 213248);   // 128 KB  -> 344320

    k1_stats<<<NSEG, 256, 0, stream>>>(logits, ent_memo, out, blockCnt,
                                       candList, rnkB, rnkM);
    k2a_count<<<dim3(NSEG + 8, NCH), 256, 0, stream>>>(ent_memo, blockCnt,
                                                       candList, rnkB, rnkM);
    k2b_scatter<<<NSEG, 256, 0, stream>>>(blockCnt, candList, rnkB, rnkM, list);
    k4_partial<<<64, 256, 0, stream>>>(list, text_memo, text_embeds, part);
    k5_cosin<<<B / 64, 256, 0, stream>>>(part, text_embeds, out);
}

// Round 10
// 52.527 us; speedup vs baseline: 1.5907x; 1.2506x over previous
//
#include <hip/hip_runtime.h>

#define B 16384
#define C 4
#define M 512
#define D 512
#define NCH 16
#define NSEG 64   // B/256 candidate segments
#define QSCALE 16777216.0f   // 2^24 fixed-point scale for deterministic atomics

// ---------------- K1: stats + segmented candidate build (no atomics) -------
__global__ __launch_bounds__(256) void k1_stats(
    const float* __restrict__ logits,
    const float* __restrict__ ent_memo,
    float* __restrict__ out,
    int* __restrict__ blockCnt,
    uint2* __restrict__ candList,
    int* __restrict__ rnkB,
    int* __restrict__ rnkM,
    unsigned long long* __restrict__ SQ)
{
    __shared__ int wscan[4];
    const int tid = threadIdx.x, blk = blockIdx.x;
    const int gid = blk * 256 + tid;

    float4 l = *reinterpret_cast<const float4*>(logits + (size_t)gid * 4);
    float m = l.x; int idx = 0;
    if (l.y > m) { m = l.y; idx = 1; }
    if (l.z > m) { m = l.z; idx = 2; }
    if (l.w > m) { m = l.w; idx = 3; }
    float e0 = expf(l.x - m), e1 = expf(l.y - m), e2 = expf(l.z - m), e3 = expf(l.w - m);
    float s = e0 + e1 + e2 + e3;
    float inv = 1.0f / s;
    float p0 = e0 * inv, p1 = e1 * inv, p2 = e2 * inv, p3 = e3 * inv;
    float lse = logf(s);
    float ent = -(p0 * (l.x - m - lse) + p1 * (l.y - m - lse)
                + p2 * (l.z - m - lse) + p3 * (l.w - m - lse));
    float4 pr = { p0, p1, p2, p3 };
    *reinterpret_cast<float4*>(out + (size_t)B * 4 + (size_t)gid * 4) = pr;
    out[(size_t)B * 8 + gid] = ent;

    rnkB[gid] = 0;
    if (gid < C * M) { rnkM[gid] = 0; SQ[gid] = 0ULL; }

    const float* Ac = ent_memo + (idx << 9);
    bool flag = ent < Ac[M - 1];
    unsigned lo = 0;
    if (flag) {
        int l0 = 0, hi = M;                  // upper_bound -> #{A <= ent}
        while (l0 < hi) { int mid = (l0 + hi) >> 1; if (Ac[mid] <= ent) l0 = mid + 1; else hi = mid; }
        lo = (unsigned)l0;
    }
    // block-level compaction (order = b ascending within segment)
    unsigned long long mask = __ballot(flag);
    int lane = tid & 63, wv = tid >> 6;
    int prefix = __popcll(mask & ((1ull << lane) - 1ull));
    if (lane == 0) wscan[wv] = __popcll(mask);
    __syncthreads();
    int base = 0;
    for (int w = 0; w < wv; w++) base += wscan[w];
    if (flag)
        candList[blk * 256 + base + prefix] =
            make_uint2(__float_as_uint(ent),
                       (lo << 16) | ((unsigned)idx << 14) | (unsigned)gid);
    if (tid == 0)
        blockCnt[blk] = wscan[0] + wscan[1] + wscan[2] + wscan[3];
}

// ---------------- K2a: pairwise stable-rank partial counts -----------------
// grid (NSEG+8, NCH): x<NSEG -> candidate-role block x; x>=NSEG -> memo rows.
__global__ __launch_bounds__(256) void k2a_count(
    const float* __restrict__ ent_memo,
    const int* __restrict__ blockCnt,
    const uint2* __restrict__ candList,
    int* __restrict__ rnkB,
    int* __restrict__ rnkM)
{
    __shared__ uint2 ch[1024];      // 4 candidate segments of this y-chunk
    const int x = blockIdx.x, y = blockIdx.y, tid = threadIdx.x;

    int s0 = blockCnt[4 * y + 0];
    int s1 = blockCnt[4 * y + 1];
    int s2 = blockCnt[4 * y + 2];
    int s3 = blockCnt[4 * y + 3];
    int o1 = s0, o2 = s0 + s1, o3 = o2 + s2, total = o3 + s3;
    for (int j = tid; j < s0; j += 256) ch[j]      = candList[(4 * y + 0) * 256 + j];
    for (int j = tid; j < s1; j += 256) ch[o1 + j] = candList[(4 * y + 1) * 256 + j];
    for (int j = tid; j < s2; j += 256) ch[o2 + j] = candList[(4 * y + 2) * 256 + j];
    for (int j = tid; j < s3; j += 256) ch[o3 + j] = candList[(4 * y + 3) * 256 + j];
    __syncthreads();

    if (x < NSEG) {
        if (tid < blockCnt[x]) {
            uint2 v = candList[x * 256 + tid];
            float e = __uint_as_float(v.x);
            int lab = (int)((v.y >> 14) & 3);
            int bidx = (int)(v.y & 0x3FFF);
            int r = 0;
            for (int i = 0; i < total; i++) {
                uint2 w = ch[i];
                float e2 = __uint_as_float(w.x);
                if ((int)((w.y >> 14) & 3) == lab &&
                    (e2 < e || (e2 == e && (int)(w.y & 0x3FFF) < bidx))) r++;
            }
            if (r) atomicAdd(&rnkB[x * 256 + tid], r);
        }
    } else {
        int t = (x - NSEG) * 256 + tid;       // [0, C*M)
        float Am = ent_memo[t];
        int mc = t >> 9;
        int rm = 0;
        for (int i = 0; i < total; i++) {
            uint2 w = ch[i];
            if ((int)((w.y >> 14) & 3) == mc && __uint_as_float(w.x) < Am) rm++;
        }
        if (rm) atomicAdd(&rnkM[t], rm);
    }
}

// ---------------- K4acc: flag-masked dense accumulate -> SQ (int64 fx) -----
// blocks 0..511: batch, seg = x>>3, colchunk q = x&7 (64 cols).
// blocks 512..575: memo, rowgroup g = (x-512)>>3 (256 rows, single label), q.
// Deterministic: per-block fp32 partials (fixed order) -> one int64 atomicAdd.
__global__ __launch_bounds__(256) void k4acc(
    const int* __restrict__ blockCnt,
    const uint2* __restrict__ candList,
    const int* __restrict__ rnkB,
    const int* __restrict__ rnkM,
    const float* __restrict__ text_memo,
    const float* __restrict__ text_embeds,
    unsigned long long* __restrict__ SQ)
{
    __shared__ int meta[256];
    const int x = blockIdx.x, tid = threadIdx.x;
    const int col0 = (x & 7) << 6;             // q*64
    const int lane = tid & 63, sg = tid >> 6;  // 4 slot-groups (waves)

    if (x < 512) {
        const int seg = x >> 3;
        {
            int cnt = blockCnt[seg];
            uint2 v = candList[(seg << 8) + tid];   // unconditional (allocated)
            int rb = rnkB[(seg << 8) + tid];        // unconditional (zeroed)
            bool kept = (tid < cnt) && ((int)(v.y >> 16) + rb < M);
            meta[tid] = kept ? (int)(((v.y >> 14) & 3) | 4u | ((v.y & 0x3FFF) << 3)) : 0;
        }
        __syncthreads();
        float a0 = 0.f, a1 = 0.f, a2 = 0.f, a3 = 0.f;
        #pragma unroll 8
        for (int k = 0; k < 64; k++) {
            int slot = (k << 2) | sg;               // wave-uniform
            int mt = meta[slot];
            int bidx = mt >> 3;
            float v = text_embeds[(size_t)bidx * D + col0 + lane]; // unkept -> row 0 (L2 hit)
            bool kept = (mt & 4) != 0;
            int lab = mt & 3;
            a0 += (kept && lab == 0) ? v : 0.f;
            a1 += (kept && lab == 1) ? v : 0.f;
            a2 += (kept && lab == 2) ? v : 0.f;
            a3 += (kept && lab == 3) ? v : 0.f;
        }
        __shared__ float red[4][4][64];             // [sg][label][lane]
        red[sg][0][lane] = a0; red[sg][1][lane] = a1;
        red[sg][2][lane] = a2; red[sg][3][lane] = a3;
        __syncthreads();
        // thread (sg=label, lane=col): fixed-order sum over the 4 slot-groups
        float t = ((red[0][sg][lane] + red[1][sg][lane])
                 + red[2][sg][lane]) + red[3][sg][lane];
        long long q = llrintf(t * QSCALE);
        atomicAdd(&SQ[(sg << 9) + col0 + lane], (unsigned long long)q);
    } else {
        const int g = (x - 512) >> 3;               // rowgroup 0..7
        const int c = g >> 1;                       // label
        const int base = g << 8;                    // first global memo row
        {
            int i = base + tid;
            meta[tid] = ((i & (M - 1)) + rnkM[i] < M) ? 1 : 0;
        }
        __syncthreads();
        float a = 0.f;
        #pragma unroll 8
        for (int k = 0; k < 64; k++) {
            int slot = (k << 2) | sg;
            float v = text_memo[(size_t)(base + slot) * D + col0 + lane];
            a += meta[slot] ? v : 0.f;
        }
        __shared__ float redm[4][64];
        redm[sg][lane] = a;
        __syncthreads();
        if (tid < 64) {
            float t = ((redm[0][tid] + redm[1][tid]) + redm[2][tid]) + redm[3][tid];
            long long q = llrintf(t * QSCALE);
            atomicAdd(&SQ[(c << 9) + col0 + tid], (unsigned long long)q);
        }
    }
}

// ---------------- K5: SQ->VGPR S + GEMV + combines + softmaxes -------------
// 1024 blocks x 256 thr (proven shape: 4 blocks/CU), 4 rows per wave.
__global__ __launch_bounds__(256) void k5_cosin(
    const unsigned long long* __restrict__ SQ,
    const float* __restrict__ text_embeds,
    float* __restrict__ out)
{
    const int tid = threadIdx.x;
    const int wave = tid >> 6, lane = tid & 63;
    const float sc = 1.0f / QSCALE;
    float s0[8], s1[8], s2[8], s3[8];
    #pragma unroll
    for (int j = 0; j < 8; j++) {
        s0[j] = (float)(long long)SQ[0 * 512 + lane * 8 + j] * sc;
        s1[j] = (float)(long long)SQ[1 * 512 + lane * 8 + j] * sc;
        s2[j] = (float)(long long)SQ[2 * 512 + lane * 8 + j] * sc;
        s3[j] = (float)(long long)SQ[3 * 512 + lane * 8 + j] * sc;
    }
    for (int r4 = 0; r4 < 4; r4++) {
        int b = blockIdx.x * 16 + wave * 4 + r4;
        const float4* te4 = reinterpret_cast<const float4*>(text_embeds + (size_t)b * D);
        float4 t0 = te4[lane * 2], t1 = te4[lane * 2 + 1];
        float te[8] = { t0.x, t0.y, t0.z, t0.w, t1.x, t1.y, t1.z, t1.w };
        float c0 = 0.f, c1 = 0.f, c2 = 0.f, c3 = 0.f;
        #pragma unroll
        for (int j = 0; j < 8; j++) {
            c0 += te[j] * s0[j];
            c1 += te[j] * s1[j];
            c2 += te[j] * s2[j];
            c3 += te[j] * s3[j];
        }
        for (int off = 32; off; off >>= 1) {
            c0 += __shfl_down(c0, off, 64);
            c1 += __shfl_down(c1, off, 64);
            c2 += __shfl_down(c2, off, 64);
            c3 += __shfl_down(c3, off, 64);
        }
        if (lane == 0) {
            float t0c = c0 + c2, t1c = c1 + c3;   // text_combine
            float v0c = c0 + c1, v1c = c2 + c3;   // vision_combine
            float tm = fmaxf(t0c, t1c);
            float te0 = expf(t0c - tm), te1 = expf(t1c - tm);
            float ts = te0 + te1;
            float mt0 = te0 / ts, mt1 = te1 / ts;
            float vm = fmaxf(v0c, v1c);
            float ve0 = expf(v0c - vm), ve1 = expf(v1c - vm);
            float vs = ve0 + ve1;
            float mv0 = ve0 / vs, mv1 = ve1 / vs;
            float4 o = { mt0 * mv0, mt1 * mv0, mt0 * mv1, mt1 * mv1 };
            *reinterpret_cast<float4*>(out + (size_t)b * 4) = o;
        }
    }
}

// ---------------------------------------------------------------------------
extern "C" void kernel_launch(void* const* d_in, const int* in_sizes, int n_in,
                              void* d_out, int out_size, void* d_ws, size_t ws_size,
                              hipStream_t stream)
{
    (void)in_sizes; (void)n_in; (void)out_size; (void)ws_size;
    const float* logits      = (const float*)d_in[0];
    const float* text_embeds = (const float*)d_in[1];
    const float* ent_memo    = (const float*)d_in[3];
    const float* text_memo   = (const float*)d_in[4];
    float* out = (float*)d_out;
    char* ws = (char*)d_ws;

    // workspace layout (bytes), 256-aligned
    int*   blockCnt = (int*)(ws + 0);                        // 256 B
    uint2* candList = (uint2*)(ws + 256);                    // 128 KB -> 131328
    int*   rnkB     = (int*)(ws + 131328);                   // 64 KB  -> 196864
    int*   rnkM     = (int*)(ws + 196864);                   // 8 KB   -> 205056
    unsigned long long* SQ = (unsigned long long*)(ws + 205056); // 16 KB -> 221440

    k1_stats<<<NSEG, 256, 0, stream>>>(logits, ent_memo, out, blockCnt,
                                       candList, rnkB, rnkM, SQ);
    k2a_count<<<dim3(NSEG + 8, NCH), 256, 0, stream>>>(ent_memo, blockCnt,
                                                       candList, rnkB, rnkM);
    k4acc<<<576, 256, 0, stream>>>(blockCnt, candList, rnkB, rnkM,
                                   text_memo, text_embeds, SQ);
    k5_cosin<<<1024, 256, 0, stream>>>(SQ, text_embeds, out);
}